// Round 13
// baseline (1487.147 us; speedup 1.0000x reference)
//
#include <hip/hip_runtime.h>
#include <math.h>

// Problem constants (B=4, D=64, H=W=64 -> m=n=4096)
#define BB 4
#define DD 64
#define MM 4096
#define M1 4097
#define NORMC 9.0109133472792788f     // log(8192)
#define CSH 11.0f                     // E = exp(d - CSH), fp8 e4m3 safe range
#define SCLX 1.0e12f                  // X -> fp8 A-operand scale
#define INVSCLX 1.0e-12f

typedef __attribute__((ext_vector_type(8))) short bf16x8;
typedef __attribute__((ext_vector_type(4))) float f32x4;

__device__ __forceinline__ f32x4 mfma16(bf16x8 a, bf16x8 b, f32x4 c) {
    return __builtin_amdgcn_mfma_f32_16x16x32_bf16(a, b, c, 0, 0, 0);
}
__device__ __forceinline__ unsigned short f2bf(float x) {
    unsigned u = __float_as_uint(x);
    u += 0x7fffu + ((u >> 16) & 1u);
    return (unsigned short)(u >> 16);
}

// ===========================================================================
// prep: transpose feats to [b][p][c] bf16 + exact f32 norms + init (S0, cnts)
// ===========================================================================
__global__ void __launch_bounds__(256)
prep_kernel(const float* __restrict__ f0, const float* __restrict__ f1,
            unsigned short* __restrict__ h0, unsigned short* __restrict__ h1,
            float* __restrict__ n0, float* __restrict__ n1,
            float* __restrict__ SK0, unsigned* __restrict__ cnt) {
    __shared__ float T[64][65];
    __shared__ float NB[4][64];
    const int b = blockIdx.y;
    const int p0 = blockIdx.x * 64;
    const int z = blockIdx.z;
    const float* src = (z == 0 ? f0 : f1) + (size_t)b * DD * MM;
    unsigned short* dh = (z == 0 ? h0 : h1) + (size_t)b * MM * DD;
    const int tid = threadIdx.x;
#pragma unroll
    for (int l = 0; l < 16; ++l) {
        int idx = l * 256 + tid;
        T[idx >> 6][idx & 63] = src[(idx >> 6) * MM + p0 + (idx & 63)];
    }
    __syncthreads();
    // norms partial (exact f32 from pre-rounded values)
    {
        const int p = tid & 63, seg = tid >> 6;
        float nn = 0.f;
#pragma unroll
        for (int c = 0; c < 16; ++c) {
            float v = T[seg * 16 + c][p];
            nn = fmaf(v, v, nn);
        }
        NB[seg][p] = nn;
    }
    // bf16 pack
    const int p = tid >> 2;
    const int cs = (tid & 3) * 16;
    unsigned hw[8];
#pragma unroll
    for (int k = 0; k < 8; ++k) {
        unsigned short a = f2bf(T[cs + 2 * k][p]);
        unsigned short c = f2bf(T[cs + 2 * k + 1][p]);
        hw[k] = (unsigned)a | ((unsigned)c << 16);
    }
    __syncthreads();
    if (tid < 64) {
        float n = NB[0][tid] + NB[1][tid] + NB[2][tid] + NB[3][tid];
        (z == 0 ? n0 : n1)[b * MM + p0 + tid] = n;
    }
    size_t base = (size_t)(p0 + p) * DD + cs;
    *(uint4*)(dh + base)     = make_uint4(hw[0], hw[1], hw[2], hw[3]);
    *(uint4*)(dh + base + 8) = make_uint4(hw[4], hw[5], hw[6], hw[7]);
    if (blockIdx.x == 0 && b == 0 && z == 0) {
        if (tid < 8) SK0[tid] = 1.0f;
        if (tid >= 8 && tid < 24) cnt[tid - 8] = 0u;
    }
}

// ===========================================================================
// EB layout: fp8 MFMA B-fragments. Tile = 32 rows (i) x 16 cols (j).
// EB[((b*128 + ig)*256 + jt)*64 + l] is a uint2 (8 bytes): lane l=(lg,lc),
// byte t holds E[i = ig*32 + 8*lg + t][j = jt*16 + lc].
// ===========================================================================
__global__ void __launch_bounds__(256)
distEB_kernel(const unsigned short* __restrict__ h0, const unsigned short* __restrict__ h1,
              const float* __restrict__ n0, const float* __restrict__ n1,
              uint2* __restrict__ EB) {
    __shared__ unsigned char sc[4][640];       // per-wave transpose scratch (stride 40)
    const int id = blockIdx.x;
    const int xcd = id & 7, slot = id >> 3;
    const int b = xcd >> 1;
    const int x = slot * 2 + (xcd & 1);        // 0..127
    const int r0 = x * 32;
    const int tid = threadIdx.x;
    const int w = tid >> 6, l = tid & 63, lg = l >> 4, lc = l & 15;
    const size_t fb = (size_t)b * MM * DD;

    bf16x8 Ah[2][2];
    float n0r[2][4];
#pragma unroll
    for (int st = 0; st < 2; ++st) {
        const unsigned short* pa = h0 + fb + (size_t)(r0 + st * 16 + lc) * DD + 8 * lg;
        Ah[st][0] = *(const bf16x8*)pa; Ah[st][1] = *(const bf16x8*)(pa + 32);
#pragma unroll
        for (int e = 0; e < 4; ++e)
            n0r[st][e] = n0[b * MM + r0 + st * 16 + 4 * lg + e];
    }

    for (int tt = 0; tt < 64; ++tt) {
        const int jt = w * 64 + tt;
        const int j0 = jt * 16;
        const unsigned short* pb = h1 + fb + (size_t)(j0 + lc) * DD + 8 * lg;
        bf16x8 Bh0 = *(const bf16x8*)pb, Bh1 = *(const bf16x8*)(pb + 32);
        float n1j = n1[b * MM + j0 + lc];
        unsigned pk[2];
#pragma unroll
        for (int st = 0; st < 2; ++st) {
            f32x4 acc = {0.f, 0.f, 0.f, 0.f};
            acc = mfma16(Ah[st][0], Bh0, acc);
            acc = mfma16(Ah[st][1], Bh1, acc);
            float Ev[4];
#pragma unroll
            for (int e = 0; e < 4; ++e) {
                float d2 = fmaxf(__builtin_fmaf(-2.f, acc[e], n0r[st][e] + n1j), 0.f);
                Ev[e] = __expf(sqrtf(d2) - CSH);
            }
            int p = __builtin_amdgcn_cvt_pk_fp8_f32(Ev[0], Ev[1], 0, false);
            p = __builtin_amdgcn_cvt_pk_fp8_f32(Ev[2], Ev[3], p, true);
            pk[st] = (unsigned)p;
        }
        *(unsigned*)&sc[w][lc * 40 + 4 * lg]      = pk[0];
        *(unsigned*)&sc[w][lc * 40 + 16 + 4 * lg] = pk[1];
        uint2 v = *(const uint2*)&sc[w][lc * 40 + 8 * lg];
        EB[(((size_t)(b * 128 + x)) * 256 + jt) * 64 + l] = v;
    }
}

// ===========================================================================
// Fused Sinkhorn iteration: row phase -> X; col phase -> psum; then the last
// 64 blocks (ticket-based) reduce psum -> W and update the dustbin scalars.
// All sums have fixed order -> bit-deterministic regardless of scheduling.
// ===========================================================================
__global__ void __launch_bounds__(512)
sinkF2_kernel(const uint2* __restrict__ EB, float* __restrict__ W,
              float* __restrict__ X, const float* __restrict__ SkP,
              float* __restrict__ SkC, float* __restrict__ swp,
              float* __restrict__ sxp, float* __restrict__ psum,
              unsigned* __restrict__ cnt, const float* __restrict__ bin, int first) {
    __shared__ float Wl[4096];
    __shared__ float ps[256];
    __shared__ float XL[32];
    __shared__ float CS2[2][256];
    __shared__ float shS[2];
    __shared__ unsigned shTick;
    const int bid = blockIdx.x;                // 0..511
    const int b = bid >> 7, x = bid & 127;
    const int tid = threadIdx.x;
    const int w = tid >> 6, l = tid & 63, lg = l >> 4, lc = l & 15;
    const float bs = *bin;
    const float KC = __expf(-NORMC - CSH);
    const float EBt = __expf(bs - CSH);
    const float HB = 0.5f * __expf(-bs);
    const float wMMp = first ? 1.0f : SkP[4 + b];

    if (first) {
#pragma unroll
        for (int k = 0; k < 8; ++k) Wl[k * 512 + tid] = 1.0f;
    } else {
#pragma unroll
        for (int k = 0; k < 8; ++k) Wl[k * 512 + tid] = W[b * MM + k * 512 + tid];
    }
    __syncthreads();

    const uint2* EP = EB + (((size_t)(b * 128 + x)) * 256 + w * 32) * 64 + l;
    uint2 ec[32];
#pragma unroll
    for (int k = 0; k < 32; ++k) ec[k] = EP[(size_t)k * 64];

    // ---- row phase ----
    float rs[8] = {};
#pragma unroll
    for (int k = 0; k < 32; ++k) {
        float wv = Wl[(w * 32 + k) * 16 + lc];
        auto p0 = __builtin_amdgcn_cvt_pk_f32_fp8((int)ec[k].x, false);
        auto p1 = __builtin_amdgcn_cvt_pk_f32_fp8((int)ec[k].x, true);
        auto p2 = __builtin_amdgcn_cvt_pk_f32_fp8((int)ec[k].y, false);
        auto p3 = __builtin_amdgcn_cvt_pk_f32_fp8((int)ec[k].y, true);
        rs[0] = fmaf(p0[0], wv, rs[0]); rs[1] = fmaf(p0[1], wv, rs[1]);
        rs[2] = fmaf(p1[0], wv, rs[2]); rs[3] = fmaf(p1[1], wv, rs[3]);
        rs[4] = fmaf(p2[0], wv, rs[4]); rs[5] = fmaf(p2[1], wv, rs[5]);
        rs[6] = fmaf(p3[0], wv, rs[6]); rs[7] = fmaf(p3[1], wv, rs[7]);
    }
#pragma unroll
    for (int off = 1; off < 16; off <<= 1)
#pragma unroll
        for (int t = 0; t < 8; ++t) rs[t] += __shfl_xor(rs[t], off);
    if (lc == 0) {
#pragma unroll
        for (int t = 0; t < 8; ++t) ps[w * 32 + 8 * lg + t] = rs[t];
    }
    __syncthreads();
    if (tid < 32) {
        float s = 0.f;
#pragma unroll
        for (int k = 0; k < 8; ++k) s += ps[k * 32 + tid];
        float xv = KC / (s + EBt * wMMp);
        X[b * MM + x * 32 + tid] = xv;
        XL[tid] = xv * SCLX;
        float t = xv;
#pragma unroll
        for (int off = 1; off < 32; off <<= 1) t += __shfl_xor(t, off);
        if (tid == 0) sxp[bid] = t;
        float wv = Wl[x * 32 + tid];
#pragma unroll
        for (int off = 1; off < 32; off <<= 1) wv += __shfl_xor(wv, off);
        if (tid == 0) swp[bid] = wv;
    }
    __syncthreads();

    // ---- col phase: one fp8 MFMA per tile, A = broadcast Xs ----
    {
        float f0 = XL[8 * lg + 0], f1 = XL[8 * lg + 1];
        float f2 = XL[8 * lg + 2], f3 = XL[8 * lg + 3];
        float f4 = XL[8 * lg + 4], f5 = XL[8 * lg + 5];
        float f6 = XL[8 * lg + 6], f7 = XL[8 * lg + 7];
        int u0 = __builtin_amdgcn_cvt_pk_fp8_f32(f0, f1, 0, false);
        u0 = __builtin_amdgcn_cvt_pk_fp8_f32(f2, f3, u0, true);
        int u1 = __builtin_amdgcn_cvt_pk_fp8_f32(f4, f5, 0, false);
        u1 = __builtin_amdgcn_cvt_pk_fp8_f32(f6, f7, u1, true);
        long long av = (long long)(((unsigned long long)(unsigned)u1 << 32) | (unsigned)u0);
        float* po = psum + (size_t)bid * MM;
        const f32x4 zero = {0.f, 0.f, 0.f, 0.f};
#pragma unroll
        for (int k = 0; k < 32; ++k) {
            long long bv = (long long)(((unsigned long long)ec[k].y << 32) | ec[k].x);
            f32x4 c = __builtin_amdgcn_mfma_f32_16x16x32_fp8_fp8(av, bv, zero, 0, 0, 0);
            if (l < 16) po[(w * 32 + k) * 16 + l] = c[0];
        }
    }

    // ---- ticket barrier: last 64 blocks become finishers ----
    __syncthreads();
    __threadfence();
    if (tid == 0) shTick = atomicAdd(cnt, 1u);
    __syncthreads();
    const unsigned tick = shTick;
    if (tick < 448u) return;
    if (tid == 0) {
        while (__hip_atomic_load(cnt, __ATOMIC_ACQUIRE, __HIP_MEMORY_SCOPE_AGENT) < 512u)
            __builtin_amdgcn_s_sleep(8);
    }
    __syncthreads();
    __threadfence();

    const int fb = (int)tick - 448;            // 0..63, each exactly once
    const int fbb = fb >> 4;                   // batch
    const int slice = fb & 15;                 // 256-column slice
    const float wMMpF = first ? 1.0f : SkP[4 + fbb];
    if (tid < 64) {
        float s = swp[fbb * 128 + tid] + swp[fbb * 128 + 64 + tid];
#pragma unroll
        for (int off = 1; off < 64; off <<= 1) s += __shfl_xor(s, off);
        if (tid == 0) shS[0] = HB / (s + wMMpF);          // X_MM_k
    } else if (tid < 128) {
        int t2 = tid - 64;
        float s = sxp[fbb * 128 + t2] + sxp[fbb * 128 + 64 + t2];
#pragma unroll
        for (int off = 1; off < 64; off <<= 1) s += __shfl_xor(s, off);
        if (t2 == 0) shS[1] = s;                          // sum X_k
    }
    __syncthreads();
    const float xmmK = shS[0];
    if (slice == 0 && tid == 0) {
        SkC[fbb] = xmmK;
        SkC[4 + fbb] = HB / (shS[1] + xmmK);              // W_MM_k
    }
    {
        const int c = tid & 255;
        const int h = tid >> 8;
        const float* pp = psum + ((size_t)(fbb * 128 + h * 64)) * MM + slice * 256 + c;
        float s = 0.f;
#pragma unroll 8
        for (int q = 0; q < 64; ++q) s += pp[(size_t)q * MM];
        CS2[h][c] = s;
    }
    __syncthreads();
    if (tid < 256) {
        float t2 = CS2[0][tid] + CS2[1][tid];
        W[fbb * MM + slice * 256 + tid] = KC / fmaf(t2, INVSCLX, EBt * xmmK);
    }
}

// ===========================================================================
// gamma: main blocks (0..511) + edge blocks (512..640); last block reduces
// the loss partials -> out.
// ===========================================================================
__global__ void __launch_bounds__(256)
finEB2_kernel(const uint2* __restrict__ EB, const float* __restrict__ X,
              const float* __restrict__ W, const float* __restrict__ S,
              const float* __restrict__ bin, float* __restrict__ G,
              float* __restrict__ pA, float* __restrict__ pB,
              unsigned* __restrict__ cnt, float* __restrict__ out) {
    __shared__ float T[256][36];
    __shared__ float Wl[4096];
    __shared__ float XL[32];
    __shared__ float a0[4], a1[4], a2[4], a3[4];
    __shared__ unsigned tk;
    const int bid = blockIdx.x;
    const int tid = threadIdx.x;
    const int w = tid >> 6, l = tid & 63, lg = l >> 4, lc = l & 15;
    const float bs = *bin;

    if (bid >= BB * 128) {
        // ---- edge path: last row + last col + corner ----
        const int eb = bid - BB * 128;
        const float CC = __expf(NORMC + bs);
        int t = eb * 256 + tid;
        float pc = 0.f, pr = 0.f;
        if (t < BB * M1) {
            int b = t / M1, j = t % M1;
            float wj = (j < MM) ? W[b * MM + j] : S[4 + b];
            float g = CC * S[b] * wj;
            G[((size_t)b * M1 + MM) * M1 + j] = g;
            if (j == MM) pc += g;
        } else if (t < BB * M1 + BB * MM) {
            int q = t - BB * M1;
            int b = q / MM, i = q % MM;
            float g = CC * X[b * MM + i] * S[4 + b];
            G[((size_t)b * M1 + i) * M1 + MM] = g;
            pc += g; pr += g;
        }
#pragma unroll
        for (int off = 1; off < 64; off <<= 1) {
            pc += __shfl_xor(pc, off);
            pr += __shfl_xor(pr, off);
        }
        if (l == 0) { a0[w] = pc; a1[w] = pr; }
        __syncthreads();
        if (tid == 0) {
            pB[eb * 2 + 0] = a0[0] + a0[1] + a0[2] + a0[3];
            pB[eb * 2 + 1] = a1[0] + a1[1] + a1[2] + a1[3];
        }
    } else {
        const int b = bid >> 7, x = bid & 127;
#pragma unroll
        for (int k = 0; k < 16; ++k) Wl[k * 256 + tid] = W[b * MM + k * 256 + tid];
        if (tid < 32) XL[tid] = X[b * MM + x * 32 + tid] * __expf(NORMC + CSH);
        __syncthreads();

        const uint2* EBb = EB + ((size_t)(b * 128 + x)) * 256 * 64;
        float pm = 0.f, pr = 0.f;
        for (int ch = 0; ch < 16; ++ch) {
#pragma unroll
            for (int q = 0; q < 4; ++q) {
                const int jt = ch * 16 + w * 4 + q;
                uint2 ev = EBb[(size_t)jt * 64 + l];
                float wv = Wl[jt * 16 + lc];
                auto p0 = __builtin_amdgcn_cvt_pk_f32_fp8((int)ev.x, false);
                auto p1 = __builtin_amdgcn_cvt_pk_f32_fp8((int)ev.x, true);
                auto p2 = __builtin_amdgcn_cvt_pk_f32_fp8((int)ev.y, false);
                auto p3 = __builtin_amdgcn_cvt_pk_f32_fp8((int)ev.y, true);
                float Ef[8] = {p0[0], p0[1], p1[0], p1[1], p2[0], p2[1], p3[0], p3[1]};
                float g[8];
#pragma unroll
                for (int t = 0; t < 8; ++t) {
                    g[t] = Ef[t] * XL[8 * lg + t] * wv;
                    pm = fmaf(g[t], (Ef[t] > 0.f) ? (CSH + __logf(Ef[t])) : 0.f, pm);
                    pr += g[t];
                }
                const int jl = (w * 4 + q) * 16 + lc;
                f32x4 v0 = {g[0], g[1], g[2], g[3]};
                f32x4 v1 = {g[4], g[5], g[6], g[7]};
                *(f32x4*)&T[jl][8 * lg]     = v0;
                *(f32x4*)&T[jl][8 * lg + 4] = v1;
            }
            __syncthreads();
            float* gb = G + ((size_t)(b * M1 + x * 32)) * M1 + ch * 256 + tid;
#pragma unroll
            for (int r = 0; r < 32; ++r) gb[(size_t)r * M1] = T[tid][r];
            __syncthreads();
        }
#pragma unroll
        for (int off = 1; off < 64; off <<= 1) {
            pm += __shfl_xor(pm, off);
            pr += __shfl_xor(pr, off);
        }
        if (l == 0) { a0[w] = pm; a1[w] = pr; }
        __syncthreads();
        if (tid == 0) {
            pA[bid * 2 + 0] = a0[0] + a0[1] + a0[2] + a0[3];
            pA[bid * 2 + 1] = a1[0] + a1[1] + a1[2] + a1[3];
        }
    }

    // ---- last-block final reduction -> out ----
    __syncthreads();
    __threadfence();
    if (tid == 0) tk = atomicAdd(cnt, 1u);
    __syncthreads();
    if (tk != (unsigned)(BB * 128 + 129 - 1)) return;
    __threadfence();
    float pm = 0.f, prA = 0.f, pc = 0.f, prB = 0.f;
    for (int r = tid; r < BB * 128; r += 256) { pm += pA[2 * r]; prA += pA[2 * r + 1]; }
    for (int r = tid; r < 129; r += 256)      { pc += pB[2 * r]; prB += pB[2 * r + 1]; }
#pragma unroll
    for (int off = 1; off < 64; off <<= 1) {
        pm += __shfl_xor(pm, off);
        prA += __shfl_xor(prA, off);
        pc += __shfl_xor(pc, off);
        prB += __shfl_xor(prB, off);
    }
    __syncthreads();
    if (l == 0) { a0[w] = pm; a1[w] = prA; a2[w] = pc; a3[w] = prB; }
    __syncthreads();
    if (tid == 0) {
        float PM = a0[0] + a0[1] + a0[2] + a0[3];
        float PRA = a1[0] + a1[1] + a1[2] + a1[3];
        float PC = a2[0] + a2[1] + a2[2] + a2[3];
        float PRB = a3[0] + a3[1] + a3[2] + a3[3];
        out[0] = PM / (4.0f * 4096.0f);
        out[1] = PC / (4.0f * 4097.0f) + (PRA + PRB) / (4.0f * 4096.0f * 4097.0f);
    }
}

// ===========================================================================
extern "C" void kernel_launch(void* const* d_in, const int* in_sizes, int n_in,
                              void* d_out, int out_size, void* d_ws, size_t ws_size,
                              hipStream_t stream) {
    const float* feat0 = (const float*)d_in[0];
    const float* feat1 = (const float*)d_in[1];
    const float* bin   = (const float*)d_in[2];
    float* out = (float*)d_out;
    float* G   = out + 2;                      // gamma region [4][4097][4097]
    float* ws  = (float*)d_ws;

    // ws layout (float offsets), ~80 MB total
    const size_t OF_X   = 0;                   // 16384
    const size_t OF_W   = 16384;               // 16384
    const size_t OF_SK  = 32768;               // 11*8 = 88 (pad 96)
    const size_t OF_SWP = 32864;               // 512
    const size_t OF_SXP = 33376;               // 512
    const size_t OF_CNT = 33888;               // 16 (unsigned)
    const size_t OF_PA  = 33904;               // 1024
    const size_t OF_PB  = 34928;               // 272
    const size_t OF_N0  = 35200;               // 16384
    const size_t OF_N1  = 51584;               // 16384
    const size_t OF_PS  = 67968;               // 512*4096 = 2097152
    const size_t OF_BF  = 2165120;             // 2 x 1M ushorts = 1048576 floats
    const size_t OF_E8  = 3213696;             // EB: 64MB = 16777216 floats

    float* X   = ws + OF_X;
    float* W   = ws + OF_W;
    float* SK  = ws + OF_SK;
    float* SWP = ws + OF_SWP;
    float* SXP = ws + OF_SXP;
    unsigned* CNT = (unsigned*)(ws + OF_CNT);
    float* pA  = ws + OF_PA;
    float* pB  = ws + OF_PB;
    float* n0  = ws + OF_N0;
    float* n1  = ws + OF_N1;
    float* PS  = ws + OF_PS;
    unsigned short* h0 = (unsigned short*)(ws + OF_BF);
    unsigned short* h1 = h0 + 1048576;
    uint2* EB = (uint2*)(ws + OF_E8);

    prep_kernel<<<dim3(64, BB, 2), 256, 0, stream>>>(feat0, feat1, h0, h1, n0, n1, SK, CNT);
    distEB_kernel<<<512, 256, 0, stream>>>(h0, h1, n0, n1, EB);
    for (int k = 1; k <= 10; ++k) {
        sinkF2_kernel<<<512, 512, 0, stream>>>(
            EB, W, X, SK + (size_t)(k - 1) * 8, SK + (size_t)k * 8,
            SWP, SXP, PS, CNT + (k - 1), bin, (k == 1) ? 1 : 0);
    }
    finEB2_kernel<<<BB * 128 + 129, 256, 0, stream>>>(
        EB, X, W, SK + 80, bin, G, pA, pB, CNT + 10, out);
}

// Round 14
// 372.391 us; speedup vs baseline: 3.9935x; 3.9935x over previous
//
#include <hip/hip_runtime.h>
#include <math.h>

// Problem constants (B=4, D=64, H=W=64 -> m=n=4096)
#define BB 4
#define DD 64
#define MM 4096
#define M1 4097
#define NORMC 9.0109133472792788f     // log(8192)
#define CSH 11.0f                     // E = exp(d - CSH), fp8 e4m3 safe range
#define SCLX 1.0e12f                  // X -> fp8 A-operand scale (X ~ 3.7e-13)
#define INVSCLX 1.0e-12f

typedef __attribute__((ext_vector_type(8))) short bf16x8;
typedef __attribute__((ext_vector_type(4))) float f32x4;

__device__ __forceinline__ f32x4 mfma16(bf16x8 a, bf16x8 b, f32x4 c) {
    return __builtin_amdgcn_mfma_f32_16x16x32_bf16(a, b, c, 0, 0, 0);
}
__device__ __forceinline__ unsigned short f2bf(float x) {
    unsigned u = __float_as_uint(x);
    u += 0x7fffu + ((u >> 16) & 1u);
    return (unsigned short)(u >> 16);
}

// ===========================================================================
// prep: transpose feats to [b][p][c] bf16 (hi only)
// ===========================================================================
__global__ void __launch_bounds__(256)
prep_kernel(const float* __restrict__ f0, const float* __restrict__ f1,
            unsigned short* __restrict__ h0, unsigned short* __restrict__ h1) {
    __shared__ float T[64][65];
    const int b = blockIdx.y;
    const int p0 = blockIdx.x * 64;
    const float* src = (blockIdx.z == 0 ? f0 : f1) + (size_t)b * DD * MM;
    unsigned short* dh = (blockIdx.z == 0 ? h0 : h1) + (size_t)b * MM * DD;
    const int tid = threadIdx.x;
#pragma unroll
    for (int l = 0; l < 16; ++l) {
        int idx = l * 256 + tid;
        T[idx >> 6][idx & 63] = src[(idx >> 6) * MM + p0 + (idx & 63)];
    }
    __syncthreads();
    const int p = tid >> 2;
    const int cs = (tid & 3) * 16;
    unsigned hw[8];
#pragma unroll
    for (int k = 0; k < 8; ++k) {
        unsigned short a = f2bf(T[cs + 2 * k][p]);
        unsigned short c = f2bf(T[cs + 2 * k + 1][p]);
        hw[k] = (unsigned)a | ((unsigned)c << 16);
    }
    size_t base = (size_t)(p0 + p) * DD + cs;
    *(uint4*)(dh + base)     = make_uint4(hw[0], hw[1], hw[2], hw[3]);
    *(uint4*)(dh + base + 8) = make_uint4(hw[4], hw[5], hw[6], hw[7]);
}

// norms (exact f32) + init (W=1, S=1) fused
__global__ void __launch_bounds__(256)
norms_kernel(const float* __restrict__ f0, const float* __restrict__ f1,
             float* __restrict__ n0, float* __restrict__ n1,
             float* __restrict__ W, float* __restrict__ S) {
    int t = blockIdx.x * 256 + threadIdx.x;
    if (t >= BB * MM) return;
    int b = t / MM, p = t % MM;
    const float* s0 = f0 + (size_t)b * DD * MM + p;
    const float* s1 = f1 + (size_t)b * DD * MM + p;
    float a = 0.f, c = 0.f;
#pragma unroll 8
    for (int k = 0; k < DD; ++k) {
        float x = s0[(size_t)k * MM]; a = fmaf(x, x, a);
        float y = s1[(size_t)k * MM]; c = fmaf(y, y, c);
    }
    n0[t] = a; n1[t] = c;
    W[t] = 1.0f;
    if (t < 8) S[t] = 1.0f;
}

// ===========================================================================
// EB layout: fp8 MFMA B-fragments. Tile = 32 rows (i) x 16 cols (j).
// EB[((b*128 + ig)*256 + jt)*64 + l] is a uint2 (8 bytes): lane l=(lg,lc),
// byte t holds E[i = ig*32 + 8*lg + t][j = jt*16 + lc].
// ===========================================================================
__global__ void __launch_bounds__(256)
distEB_kernel(const unsigned short* __restrict__ h0, const unsigned short* __restrict__ h1,
              const float* __restrict__ n0, const float* __restrict__ n1,
              uint2* __restrict__ EB) {
    __shared__ unsigned char sc[4][640];       // per-wave transpose scratch (stride 40)
    const int id = blockIdx.x;
    const int xcd = id & 7, slot = id >> 3;
    const int b = xcd >> 1;
    const int x = slot * 2 + (xcd & 1);        // 0..127
    const int r0 = x * 32;
    const int tid = threadIdx.x;
    const int w = tid >> 6, l = tid & 63, lg = l >> 4, lc = l & 15;
    const size_t fb = (size_t)b * MM * DD;

    bf16x8 Ah[2][2];
    float n0r[2][4];
#pragma unroll
    for (int st = 0; st < 2; ++st) {
        const unsigned short* pa = h0 + fb + (size_t)(r0 + st * 16 + lc) * DD + 8 * lg;
        Ah[st][0] = *(const bf16x8*)pa; Ah[st][1] = *(const bf16x8*)(pa + 32);
#pragma unroll
        for (int e = 0; e < 4; ++e)
            n0r[st][e] = n0[b * MM + r0 + st * 16 + 4 * lg + e];
    }

    for (int tt = 0; tt < 64; ++tt) {
        const int jt = w * 64 + tt;
        const int j0 = jt * 16;
        const unsigned short* pb = h1 + fb + (size_t)(j0 + lc) * DD + 8 * lg;
        bf16x8 Bh0 = *(const bf16x8*)pb, Bh1 = *(const bf16x8*)(pb + 32);
        float n1j = n1[b * MM + j0 + lc];
        unsigned pk[2];
#pragma unroll
        for (int st = 0; st < 2; ++st) {
            f32x4 acc = {0.f, 0.f, 0.f, 0.f};
            acc = mfma16(Ah[st][0], Bh0, acc);
            acc = mfma16(Ah[st][1], Bh1, acc);
            float Ev[4];
#pragma unroll
            for (int e = 0; e < 4; ++e) {
                float d2 = fmaxf(__builtin_fmaf(-2.f, acc[e], n0r[st][e] + n1j), 0.f);
                Ev[e] = __expf(sqrtf(d2) - CSH);
            }
            int p = __builtin_amdgcn_cvt_pk_fp8_f32(Ev[0], Ev[1], 0, false);
            p = __builtin_amdgcn_cvt_pk_fp8_f32(Ev[2], Ev[3], p, true);
            pk[st] = (unsigned)p;
        }
        *(unsigned*)&sc[w][lc * 40 + 4 * lg]      = pk[0];
        *(unsigned*)&sc[w][lc * 40 + 16 + 4 * lg] = pk[1];
        uint2 v = *(const uint2*)&sc[w][lc * 40 + 8 * lg];
        EB[(((size_t)(b * 128 + x)) * 256 + jt) * 64 + l] = v;
    }
}

// ===========================================================================
// Sinkhorn iteration: row phase (VALU) + col phase (fp8 MFMA) per block.
// Block (b, x) owns rows x*32..x*32+31 and all 4096 cols. EB read ONCE.
// ===========================================================================
__global__ void __launch_bounds__(512)
sinkEB_kernel(const uint2* __restrict__ EB, const float* __restrict__ W,
              float* __restrict__ X, float* __restrict__ S,
              float* __restrict__ psum, const float* __restrict__ bin) {
    const int bid = blockIdx.x;
    const int tid = threadIdx.x;
    const float bs = *bin;
    if (bid < BB) {
        // dustbin: X_MM[b] = 0.5 e^{-bs} / (sum_j W_j + W_MM[b])
        __shared__ float am[8];
        const int b = bid;
        const int w = tid >> 6, l = tid & 63;
        float s = 0.f;
        for (int t = tid; t < MM; t += 512) s += W[b * MM + t];
#pragma unroll
        for (int off = 1; off < 64; off <<= 1) s += __shfl_xor(s, off);
        if (l == 0) am[w] = s;
        __syncthreads();
        if (tid == 0) {
            float tot = 0.f;
#pragma unroll
            for (int k = 0; k < 8; ++k) tot += am[k];
            S[b] = 0.5f * __expf(-bs) / (tot + S[4 + b]);
        }
        return;
    }
    __shared__ float Wl[4096];
    __shared__ float ps[256];
    __shared__ float XL[32];
    const int idx = bid - BB;
    const int b = idx >> 7, x = idx & 127;
    const int w = tid >> 6, l = tid & 63, lg = l >> 4, lc = l & 15;
    const float KC = __expf(-NORMC - CSH);
    const float wmm = __expf(bs - CSH) * S[4 + b];
#pragma unroll
    for (int k = 0; k < 8; ++k) Wl[k * 512 + tid] = W[b * MM + k * 512 + tid];
    __syncthreads();

    const uint2* EP = EB + (((size_t)(b * 128 + x)) * 256 + w * 32) * 64 + l;
    uint2 ec[32];
#pragma unroll
    for (int k = 0; k < 32; ++k) ec[k] = EP[(size_t)k * 64];

    // ---- row phase: rs[t] = partial sum over this wave's 512 cols ----
    float rs[8] = {};
#pragma unroll
    for (int k = 0; k < 32; ++k) {
        float wv = Wl[(w * 32 + k) * 16 + lc];
        auto p0 = __builtin_amdgcn_cvt_pk_f32_fp8((int)ec[k].x, false);
        auto p1 = __builtin_amdgcn_cvt_pk_f32_fp8((int)ec[k].x, true);
        auto p2 = __builtin_amdgcn_cvt_pk_f32_fp8((int)ec[k].y, false);
        auto p3 = __builtin_amdgcn_cvt_pk_f32_fp8((int)ec[k].y, true);
        rs[0] = fmaf(p0[0], wv, rs[0]); rs[1] = fmaf(p0[1], wv, rs[1]);
        rs[2] = fmaf(p1[0], wv, rs[2]); rs[3] = fmaf(p1[1], wv, rs[3]);
        rs[4] = fmaf(p2[0], wv, rs[4]); rs[5] = fmaf(p2[1], wv, rs[5]);
        rs[6] = fmaf(p3[0], wv, rs[6]); rs[7] = fmaf(p3[1], wv, rs[7]);
    }
#pragma unroll
    for (int off = 1; off < 16; off <<= 1)
#pragma unroll
        for (int t = 0; t < 8; ++t) rs[t] += __shfl_xor(rs[t], off);
    if (lc == 0) {
#pragma unroll
        for (int t = 0; t < 8; ++t) ps[w * 32 + 8 * lg + t] = rs[t];
    }
    __syncthreads();
    if (tid < 32) {
        float s = 0.f;
#pragma unroll
        for (int k = 0; k < 8; ++k) s += ps[k * 32 + tid];
        float xv = KC / (s + wmm);
        X[b * MM + x * 32 + tid] = xv;
        XL[tid] = xv * SCLX;
    }
    __syncthreads();

    // ---- col phase: one fp8 MFMA per tile, A = broadcast Xs ----
    float f0 = XL[8 * lg + 0], f1 = XL[8 * lg + 1];
    float f2 = XL[8 * lg + 2], f3 = XL[8 * lg + 3];
    float f4 = XL[8 * lg + 4], f5 = XL[8 * lg + 5];
    float f6 = XL[8 * lg + 6], f7 = XL[8 * lg + 7];
    int u0 = __builtin_amdgcn_cvt_pk_fp8_f32(f0, f1, 0, false);
    u0 = __builtin_amdgcn_cvt_pk_fp8_f32(f2, f3, u0, true);
    int u1 = __builtin_amdgcn_cvt_pk_fp8_f32(f4, f5, 0, false);
    u1 = __builtin_amdgcn_cvt_pk_fp8_f32(f6, f7, u1, true);
    long long av = (long long)(((unsigned long long)(unsigned)u1 << 32) | (unsigned)u0);
    float* po = psum + ((size_t)(b * 128 + x)) * MM;
    const f32x4 zero = {0.f, 0.f, 0.f, 0.f};
#pragma unroll
    for (int k = 0; k < 32; ++k) {
        long long bv = (long long)(((unsigned long long)ec[k].y << 32) | ec[k].x);
        f32x4 c = __builtin_amdgcn_mfma_f32_16x16x32_fp8_fp8(av, bv, zero, 0, 0, 0);
        if (l < 16) po[(w * 32 + k) * 16 + l] = c[0];
    }
}

// combine column partials (scaled by SCLX) -> W; extra blocks: W_MM
__global__ void __launch_bounds__(256)
wcomb_kernel(const float* __restrict__ psum, const float* __restrict__ X,
             float* __restrict__ W, float* __restrict__ S,
             const float* __restrict__ bin) {
    const int bid = blockIdx.x;
    const int tid = threadIdx.x;
    const float bs = *bin;
    if (bid < BB * 64) {
        __shared__ float ps[256];
        const int b = bid >> 6, cg = bid & 63;
        const int c64 = tid & 63, g = tid >> 6;
        const float* pp = psum + ((size_t)(b * 128 + g * 32)) * MM + cg * 64 + c64;
        float s = 0.f;
#pragma unroll
        for (int c = 0; c < 32; ++c) s += pp[(size_t)c * MM];
        ps[tid] = s;
        __syncthreads();
        if (tid < 64) {
            float t = ps[tid] + ps[tid + 64] + ps[tid + 128] + ps[tid + 192];
            t = t * INVSCLX + __expf(bs - CSH) * S[b];   // unscale + dustbin-row
            W[b * MM + cg * 64 + tid] = __expf(-NORMC - CSH) / t;
        }
    } else {
        // W_MM[b] = 0.5 e^{-bs} / (sum_i X_i + X_MM[b])
        const int b = bid - BB * 64;
        const int w = tid >> 6, l = tid & 63;
        __shared__ float am[4];
        float s = 0.f;
        for (int t = tid; t < MM; t += 256) s += X[b * MM + t];
#pragma unroll
        for (int off = 1; off < 64; off <<= 1) s += __shfl_xor(s, off);
        if (l == 0) am[w] = s;
        __syncthreads();
        if (tid == 0) {
            float tot = am[0] + am[1] + am[2] + am[3];
            S[4 + b] = 0.5f * __expf(-bs) / (tot + S[b]);
        }
    }
}

// ===========================================================================
// gamma: main block (from EB, padded LDS transpose, nt stores, no Wl)
//        + edge blocks (bid>=512)
// ===========================================================================
__global__ void __launch_bounds__(256)
finEB_kernel(const uint2* __restrict__ EB, const float* __restrict__ X,
             const float* __restrict__ W, const float* __restrict__ S,
             const float* __restrict__ bin, float* __restrict__ G,
             float* __restrict__ pA, float* __restrict__ pB) {
    const int bid = blockIdx.x;
    const int tid = threadIdx.x;
    if (bid >= BB * 128) {
        // ---- edge path: last row + last col + corner ----
        const int eb = bid - BB * 128;
        const float bs = *bin;
        const float CC = __expf(NORMC + bs);
        int t = eb * 256 + tid;
        float pc = 0.f, pr = 0.f;
        if (t < BB * M1) {
            int b = t / M1, j = t % M1;
            float wj = (j < MM) ? W[b * MM + j] : S[4 + b];
            float g = CC * S[b] * wj;
            G[((size_t)b * M1 + MM) * M1 + j] = g;
            if (j == MM) pc += g;
        } else if (t < BB * M1 + BB * MM) {
            int q = t - BB * M1;
            int b = q / MM, i = q % MM;
            float g = CC * X[b * MM + i] * S[4 + b];
            G[((size_t)b * M1 + i) * M1 + MM] = g;
            pc += g; pr += g;
        }
#pragma unroll
        for (int off = 1; off < 64; off <<= 1) {
            pc += __shfl_xor(pc, off);
            pr += __shfl_xor(pr, off);
        }
        __shared__ float e0[4], e1[4];
        if ((tid & 63) == 0) { e0[tid >> 6] = pc; e1[tid >> 6] = pr; }
        __syncthreads();
        if (tid == 0) {
            pB[eb * 2 + 0] = e0[0] + e0[1] + e0[2] + e0[3];
            pB[eb * 2 + 1] = e1[0] + e1[1] + e1[2] + e1[3];
        }
        return;
    }
    __shared__ float T[256][37];               // +1 pad: stride-37 reads are 2-way (free)
    __shared__ float XL[32];
    const int b = bid >> 7, x = bid & 127;
    const int w = tid >> 6, l = tid & 63, lg = l >> 4, lc = l & 15;
    if (tid < 32) XL[tid] = X[b * MM + x * 32 + tid] * __expf(NORMC + CSH);
    __syncthreads();

    const float* Wb = W + b * MM;              // L1-broadcast reads, no LDS staging
    const uint2* EBb = EB + ((size_t)(b * 128 + x)) * 256 * 64;
    float pm = 0.f, pr = 0.f;
    for (int ch = 0; ch < 16; ++ch) {
#pragma unroll
        for (int q = 0; q < 4; ++q) {
            const int jt = ch * 16 + w * 4 + q;
            uint2 ev = EBb[(size_t)jt * 64 + l];
            float wv = Wb[jt * 16 + lc];
            auto p0 = __builtin_amdgcn_cvt_pk_f32_fp8((int)ev.x, false);
            auto p1 = __builtin_amdgcn_cvt_pk_f32_fp8((int)ev.x, true);
            auto p2 = __builtin_amdgcn_cvt_pk_f32_fp8((int)ev.y, false);
            auto p3 = __builtin_amdgcn_cvt_pk_f32_fp8((int)ev.y, true);
            float Ef[8] = {p0[0], p0[1], p1[0], p1[1], p2[0], p2[1], p3[0], p3[1]};
            const int jl = (w * 4 + q) * 16 + lc;
#pragma unroll
            for (int t = 0; t < 8; ++t) {
                float g = Ef[t] * XL[8 * lg + t] * wv;
                T[jl][8 * lg + t] = g;
                pm = fmaf(g, (Ef[t] > 0.f) ? (CSH + __logf(Ef[t])) : 0.f, pm);
                pr += g;
            }
        }
        __syncthreads();
        float* gb = G + ((size_t)(b * M1 + x * 32)) * M1 + ch * 256 + tid;
#pragma unroll
        for (int r = 0; r < 32; ++r)
            __builtin_nontemporal_store(T[tid][r], &gb[(size_t)r * M1]);
        __syncthreads();
    }
#pragma unroll
    for (int off = 1; off < 64; off <<= 1) {
        pm += __shfl_xor(pm, off);
        pr += __shfl_xor(pr, off);
    }
    __shared__ float s0[4], s1[4];
    if (l == 0) { s0[w] = pm; s1[w] = pr; }
    __syncthreads();
    if (tid == 0) {
        pA[bid * 2 + 0] = s0[0] + s0[1] + s0[2] + s0[3];
        pA[bid * 2 + 1] = s1[0] + s1[1] + s1[2] + s1[3];
    }
}

__global__ void __launch_bounds__(256)
reduce_out_kernel(const float* __restrict__ pA, int nA,
                  const float* __restrict__ pB, int nB, float* __restrict__ out) {
    const int tid = threadIdx.x;
    float pm = 0.f, prA = 0.f, pc = 0.f, prB = 0.f;
    for (int r = tid; r < nA; r += 256) { pm += pA[2 * r]; prA += pA[2 * r + 1]; }
    for (int r = tid; r < nB; r += 256) { pc += pB[2 * r]; prB += pB[2 * r + 1]; }
#pragma unroll
    for (int off = 1; off < 64; off <<= 1) {
        pm += __shfl_xor(pm, off);
        prA += __shfl_xor(prA, off);
        pc += __shfl_xor(pc, off);
        prB += __shfl_xor(prB, off);
    }
    __shared__ float a0[4], a1[4], a2[4], a3[4];
    if ((tid & 63) == 0) {
        int w = tid >> 6;
        a0[w] = pm; a1[w] = prA; a2[w] = pc; a3[w] = prB;
    }
    __syncthreads();
    if (tid == 0) {
        float PM = a0[0] + a0[1] + a0[2] + a0[3];
        float PRA = a1[0] + a1[1] + a1[2] + a1[3];
        float PC = a2[0] + a2[1] + a2[2] + a2[3];
        float PRB = a3[0] + a3[1] + a3[2] + a3[3];
        out[0] = PM / (4.0f * 4096.0f);
        out[1] = PC / (4.0f * 4097.0f) + (PRA + PRB) / (4.0f * 4096.0f * 4097.0f);
    }
}

// ===========================================================================
extern "C" void kernel_launch(void* const* d_in, const int* in_sizes, int n_in,
                              void* d_out, int out_size, void* d_ws, size_t ws_size,
                              hipStream_t stream) {
    const float* feat0 = (const float*)d_in[0];
    const float* feat1 = (const float*)d_in[1];
    const float* bin   = (const float*)d_in[2];
    float* out = (float*)d_out;
    float* G   = out + 2;                      // gamma region [4][4097][4097]
    float* ws  = (float*)d_ws;

    // ws layout (float offsets)
    const size_t OF_X   = 0;                   // 16384
    const size_t OF_W   = 16384;               // 16384
    const size_t OF_S   = 32768;               // 8 (+pad to 64)
    const size_t OF_PA  = 32832;               // 1024
    const size_t OF_PB  = 33856;               // 272
    const size_t OF_N0  = 34128;               // 16384
    const size_t OF_N1  = 50512;               // 16384
    const size_t OF_PS  = 66896;               // 512*4096 = 2097152
    const size_t OF_BF  = 2164048;             // 2 x 1M ushorts = 1048576 floats
    const size_t OF_E8  = 3212624;             // EB: 64MB = 16777216 floats

    float* X    = ws + OF_X;
    float* W    = ws + OF_W;
    float* S    = ws + OF_S;
    float* pA   = ws + OF_PA;
    float* pB   = ws + OF_PB;
    float* n0   = ws + OF_N0;
    float* n1   = ws + OF_N1;
    float* psum = ws + OF_PS;
    unsigned short* h0 = (unsigned short*)(ws + OF_BF);
    unsigned short* h1 = h0 + 1048576;
    uint2* EB = (uint2*)(ws + OF_E8);

    prep_kernel<<<dim3(64, BB, 2), 256, 0, stream>>>(feat0, feat1, h0, h1);
    norms_kernel<<<64, 256, 0, stream>>>(feat0, feat1, n0, n1, W, S);
    distEB_kernel<<<512, 256, 0, stream>>>(h0, h1, n0, n1, EB);
    for (int it = 0; it < 10; ++it) {
        sinkEB_kernel<<<BB + BB * 128, 512, 0, stream>>>(EB, W, X, S, psum, bin);
        wcomb_kernel<<<BB * 64 + BB, 256, 0, stream>>>(psum, X, W, S, bin);
    }
    finEB_kernel<<<BB * 128 + 129, 256, 0, stream>>>(EB, X, W, S, bin, G, pA, pB);
    reduce_out_kernel<<<1, 256, 0, stream>>>(pA, BB * 128, pB, 129, out);
}